// Round 1
// baseline (623.318 us; speedup 1.0000x reference)
//
#include <hip/hip_runtime.h>

// TemporalUnfold1d: x (B, C, T) fp32 -> out (B, K*C, T), K=4, dilation=1,
// causal left pad of 3. out[b, kk*C + c, t] = x[b, c, t + kk - 3] (0 if OOB).
//
// Memory-bound: 128 MiB in + 512 MiB out (~107 us roofline at 6.3 TB/s).
// v2 strategy: one block per input row (4096 blocks x 256 threads).
//  - Each thread owns 8 float4s of the row -> 8x ILP, loads hoisted.
//  - prev float4 is the neighbor's data -> L1 hit; HBM read stays ~1x input.
//  - Stores are stream-major (all 8 chunks of one kk-slice, then the next):
//    each of the 4 output streams gets an 8 KiB sequential burst per block.
//  - Non-temporal stores: output is write-once/never-read; avoid 512 MiB of
//    L2/L3 write-allocate churn evicting the input lines we re-read.

typedef float f4 __attribute__((ext_vector_type(4)));

constexpr int K   = 4;
constexpr int C   = 256;
constexpr int T   = 8192;
constexpr int T4  = T / 4;      // 2048 float4 per row
constexpr int BLK = 256;
constexpr int U   = T4 / BLK;   // 8 float4 per thread

__global__ __launch_bounds__(BLK) void TemporalUnfold1d_kernel(
    const f4* __restrict__ x4,
    f4* __restrict__ o4) {
    const int tid = threadIdx.x;
    const int row = blockIdx.x;        // one input row (b,c) per block
    const int b   = row >> 8;          // row / C
    const int c   = row & (C - 1);     // row % C

    const f4* __restrict__ xrow = x4 + (size_t)row * T4;
    f4* __restrict__ orow = o4 + ((size_t)b * (K * C) + c) * T4;
    const size_t OS = (size_t)C * T4;  // float4 stride between kk slices (8 MiB)

    f4 cur[U];
    f4 prv[U];

#pragma unroll
    for (int u = 0; u < U; ++u) {
        const int t4 = (u << 8) + tid;
        cur[u] = xrow[t4];
        prv[u] = (t4 == 0) ? (f4){0.f, 0.f, 0.f, 0.f} : xrow[t4 - 1];
    }

    // Stream-major non-temporal stores.
#pragma unroll
    for (int kk = 0; kk < K; ++kk) {
#pragma unroll
        for (int u = 0; u < U; ++u) {
            const int t4 = (u << 8) + tid;
            const f4 p = prv[u];
            const f4 q = cur[u];
            f4 w;
            if      (kk == 0) w = (f4){p.y, p.z, p.w, q.x};  // shift -3
            else if (kk == 1) w = (f4){p.z, p.w, q.x, q.y};  // shift -2
            else if (kk == 2) w = (f4){p.w, q.x, q.y, q.z};  // shift -1
            else              w = q;                         // shift  0
            __builtin_nontemporal_store(w, &orow[(size_t)kk * OS + t4]);
        }
    }
}

extern "C" void kernel_launch(void* const* d_in, const int* in_sizes, int n_in,
                              void* d_out, int out_size, void* d_ws, size_t ws_size,
                              hipStream_t stream) {
    const f4* x4 = (const f4*)d_in[0];
    f4* o4 = (f4*)d_out;

    int rows = in_sizes[0] / T;  // B*C = 4096
    TemporalUnfold1d_kernel<<<rows, BLK, 0, stream>>>(x4, o4);
}

// Round 2
// 609.537 us; speedup vs baseline: 1.0226x; 1.0226x over previous
//
#include <hip/hip_runtime.h>

// TemporalUnfold1d: x (B, C, T) fp32 -> out (B, K*C, T), K=4, dilation=1,
// causal left pad of 3. out[b, kk*C + c, t] = x[b, c, t + kk - 3] (0 if OOB).
//
// Memory-bound: 128 MiB in + 512 MiB out (~107 us roofline at 6.3 TB/s).
// v3 strategy: one block per OUTPUT row, grid = B*K*C = 16384 blocks.
//  - Block index == output row index -> consecutive blocks write consecutive
//    32 KiB rows; each thread writes ONE sequential stream. This is exactly
//    the address pattern of the 6.2 TB/s fillBufferAligned kernel, unlike
//    v1/v2 where each thread interleaved 4 streams 8 MiB (pow-2) apart.
//  - kk is block-uniform -> scalar branch selects the shift variant; the
//    kk=3 slice skips the prev-load entirely.
//  - Input row (b,c) is read by 4 blocks spaced C=256 apart in launch order;
//    they are co-resident, so ~3 of 4 reads hit L2/L3 (input 128 MiB < L3).

typedef float f4 __attribute__((ext_vector_type(4)));

constexpr int K   = 4;
constexpr int C   = 256;
constexpr int T   = 8192;
constexpr int T4  = T / 4;      // 2048 float4 per row
constexpr int BLK = 256;
constexpr int U   = T4 / BLK;   // 8 float4 per thread

__global__ __launch_bounds__(BLK) void TemporalUnfold1d_kernel(
    const f4* __restrict__ x4,
    f4* __restrict__ o4) {
    const int tid = threadIdx.x;
    const int bi  = blockIdx.x;          // == output row index
    const int c   = bi & (C - 1);        // bi % C
    const int bk  = bi >> 8;             // bi / C
    const int kk  = bk & (K - 1);        // kernel position (block-uniform)
    const int b   = bk >> 2;             // batch

    const f4* __restrict__ xrow = x4 + ((size_t)(b * C + c)) * T4;
    f4* __restrict__ orow = o4 + (size_t)bi * T4;

    f4 cur[U];
#pragma unroll
    for (int u = 0; u < U; ++u) cur[u] = xrow[(u << 8) + tid];

    if (kk == 3) {
        // shift 0: pure copy
#pragma unroll
        for (int u = 0; u < U; ++u) orow[(u << 8) + tid] = cur[u];
        return;
    }

    f4 prv[U];
#pragma unroll
    for (int u = 0; u < U; ++u) {
        const int t4 = (u << 8) + tid;
        prv[u] = (t4 == 0) ? (f4){0.f, 0.f, 0.f, 0.f} : xrow[t4 - 1];
    }

    if (kk == 0) {
#pragma unroll
        for (int u = 0; u < U; ++u) {
            const f4 p = prv[u], q = cur[u];
            orow[(u << 8) + tid] = (f4){p.y, p.z, p.w, q.x};  // shift -3
        }
    } else if (kk == 1) {
#pragma unroll
        for (int u = 0; u < U; ++u) {
            const f4 p = prv[u], q = cur[u];
            orow[(u << 8) + tid] = (f4){p.z, p.w, q.x, q.y};  // shift -2
        }
    } else {
#pragma unroll
        for (int u = 0; u < U; ++u) {
            const f4 p = prv[u], q = cur[u];
            orow[(u << 8) + tid] = (f4){p.w, q.x, q.y, q.z};  // shift -1
        }
    }
}

extern "C" void kernel_launch(void* const* d_in, const int* in_sizes, int n_in,
                              void* d_out, int out_size, void* d_ws, size_t ws_size,
                              hipStream_t stream) {
    const f4* x4 = (const f4*)d_in[0];
    f4* o4 = (f4*)d_out;

    int rows = in_sizes[0] / T;  // B*C = 4096
    TemporalUnfold1d_kernel<<<rows * K, BLK, 0, stream>>>(x4, o4);
}